// Round 14
// baseline (22.491 us; speedup 1.0000x reference)
//
#include <hip/hip_runtime.h>

#define NB 32
#define NA 3
#define NGH 76
#define NGW 76
#define NT 48
#define PLANE (NGH * NGW)          // 5776
#define NCELL (NB * NA * PLANE)    // 554496
#define NOUT  (NCELL * 6)          // 3326976
#define CPT 2                      // cells per thread (consecutive pair)
#define BLK 256                    // 4 waves; 1083 blocks
#define NTHREAD (NCELL / CPT)      // 277248
#define NBLKS (NTHREAD / BLK)      // 1083
#define MAGIC 0x59A10C47u

static_assert(NTHREAD % BLK == 0, "grid must divide evenly");
static_assert(5 * BLK >= NBLKS, "poll covers all flags in one unrolled pass");

// ---------------- DIAGNOSTIC: stripped decode+store-only kernel ----------------
// Rewrites bit-identical `out` values (same math as the full kernel's decode
// phase). No LDS, no barrier, no CSR/loss/reduction/flags. Its marginal cost
// in this double-launch isolates the streaming phase of the body.
__launch_bounds__(BLK)
__global__ void yolo_decode_only(const float* __restrict__ x,
                                 float* __restrict__ out) {
    const int tx  = threadIdx.x;
    const int tid = blockIdx.x * BLK + tx;
    const int g   = tid * CPT;

    const int gw0 = g % NGW;
    const int gh  = (g / NGW) % NGH;
    const int a   = (g / PLANE) % NA;
    const int b   = g / (NA * PLANE);

    const float* xp = x + (size_t)(b * (NA * 6) + a * 6) * PLANE + (g % PLANE);
    const float2 v0 = *(const float2*)(xp);
    const float2 v1 = *(const float2*)(xp + PLANE);
    const float2 v2 = *(const float2*)(xp + 2 * PLANE);
    const float2 v3 = *(const float2*)(xp + 3 * PLANE);
    const float2 v4 = *(const float2*)(xp + 4 * PLANE);
    const float2 v5 = *(const float2*)(xp + 5 * PLANE);

    const float p0[CPT] = {v0.x, v0.y};
    const float p1[CPT] = {v1.x, v1.y};
    const float p2[CPT] = {v2.x, v2.y};
    const float p3[CPT] = {v3.x, v3.y};
    const float p4[CPT] = {v4.x, v4.y};
    const float p5[CPT] = {v5.x, v5.y};

    const float sa_w = (a == 0) ? 1.25f  : ((a == 1) ? 2.0f  : 4.125f);
    const float sa_h = (a == 0) ? 1.625f : ((a == 1) ? 3.75f : 2.875f);

    float o12[CPT * 6];
    #pragma unroll
    for (int c = 0; c < CPT; ++c) {
        const float cx    = 1.0f / (1.0f + __expf(-p0[c]));
        const float cy    = 1.0f / (1.0f + __expf(-p1[c]));
        const float pconf = 1.0f / (1.0f + __expf(-p4[c]));
        const float pcls  = 1.0f / (1.0f + __expf(-p5[c]));
        const float bx = cx + (float)(gw0 + c);
        const float by = cy + (float)gh;
        const float bw = __expf(p2[c]) * sa_w;
        const float bh = __expf(p3[c]) * sa_h;
        o12[c * 6 + 0] = bx * 8.0f;
        o12[c * 6 + 1] = by * 8.0f;
        o12[c * 6 + 2] = bw * 8.0f;
        o12[c * 6 + 3] = bh * 8.0f;
        o12[c * 6 + 4] = pconf;
        o12[c * 6 + 5] = pcls;
    }

    float4* ob = (float4*)(out + (size_t)g * 6);
    ob[0] = make_float4(o12[0], o12[1], o12[2],  o12[3]);
    ob[1] = make_float4(o12[4], o12[5], o12[6],  o12[7]);
    ob[2] = make_float4(o12[8], o12[9], o12[10], o12[11]);
}

// st layout per target (16 floats):
// 0: timg  1: valid  2: bi  3: gj  4: gi  5: tx  6: ty  7: tw  8: th  9: sc
// 10..13: x1 y1 x2 y2 (normalized xyxy)  14: area  15: pad

__launch_bounds__(BLK, 6)
__global__ void yolo_main(const float* __restrict__ x,
                          const float* __restrict__ tgt,
                          float* __restrict__ out,
                          float* __restrict__ partials,      // [NBLKS][4]
                          unsigned int* __restrict__ flags,  // [NBLKS]
                          float* __restrict__ lossbuf) {
    __shared__ float st[NT * 16];
    __shared__ unsigned long long sball[NB];
    __shared__ int soff[NB + 1];
    __shared__ int sord[NT];
    __shared__ float red[4][4];
    __shared__ float4 stage[BLK * 3];         // 12KB output tile staging

    const int tx  = threadIdx.x;
    const int bid = blockIdx.x;
    const int tid = bid * BLK + tx;
    const int g   = tid * CPT;                // first of 2 consecutive cells (even)

    const int gw0 = g % NGW;                  // even, pair never straddles a row
    const int gh  = (g / NGW) % NGH;
    const int a   = (g / PLANE) % NA;
    const int b   = g / (NA * PLANE);

    // ---------- vectorized channel loads (issue before target prep) ----------
    const float* xp = x + (size_t)(b * (NA * 6) + a * 6) * PLANE + (g % PLANE);
    const float2 v0 = *(const float2*)(xp);
    const float2 v1 = *(const float2*)(xp + PLANE);
    const float2 v2 = *(const float2*)(xp + 2 * PLANE);
    const float2 v3 = *(const float2*)(xp + 3 * PLANE);
    const float2 v4 = *(const float2*)(xp + 4 * PLANE);
    const float2 v5 = *(const float2*)(xp + 5 * PLANE);

    // ---------- wave 0: target prep + per-image CSR (ballot-based) ----------
    if (tx < 64) {
        const int t = tx;
        const bool isT = (t < NT);
        int timg = 999;                       // sentinel: matches no image
        if (isT) {
            const float t00 = tgt[0];
            const float* tr = tgt + t * 6;
            timg = (int)(tr[0] - t00);
            const float bxn = tr[1], byn = tr[2], bwn = tr[3], bhn = tr[4];

            const float gx = bxn * (float)NGW;
            const float gy = byn * (float)NGH;
            const int gi = (int)gx;
            const int gj = (int)gy;
            const float tarea = bwn * bhn;

            const float aw_px[9] = {10.f,16.f,33.f,30.f,62.f,59.f,116.f,156.f,373.f};
            const float ah_px[9] = {13.f,30.f,23.f,61.f,45.f,119.f,90.f,198.f,326.f};
            int bidx = 0; float biou = -1e30f;
            #pragma unroll
            for (int k = 0; k < 9; ++k) {
                const float aw = aw_px[k] / 608.0f;
                const float ah = ah_px[k] / 608.0f;
                const float wi = fminf(aw, bwn) * fminf(ah, bhn);
                const float un = ((aw * ah + 1e-16f) + tarea) - wi;
                const float iou = wi / un;
                if (iou > biou) { biou = iou; bidx = k; }
            }
            const bool inm = (bidx >= 0) && (bidx <= 2);
            const bool valid = inm && (gi < NGW) && (gj < NGH) && (gi >= 0) && (gj >= 0);
            const int bic = bidx < 0 ? 0 : (bidx > 2 ? 2 : bidx);
            const float apw = (bic == 0) ? 10.f : ((bic == 1) ? 16.f : 33.f);
            const float aph = (bic == 0) ? 13.f : ((bic == 1) ? 30.f : 23.f);

            float* s = st + t * 16;
            s[0]  = (float)timg;
            s[1]  = valid ? 1.0f : 0.0f;
            s[2]  = (float)bidx;
            s[3]  = (float)gj;
            s[4]  = (float)gi;
            s[5]  = gx - floorf(gx);
            s[6]  = gy - floorf(gy);
            s[7]  = __logf(((bwn * (float)NGW) * 8.0f) / apw + 1e-16f);
            s[8]  = __logf(((bhn * (float)NGH) * 8.0f) / aph + 1e-16f);
            s[9]  = 2.0f - bwn * bhn;
            s[10] = bxn - bwn * 0.5f;
            s[11] = byn - bhn * 0.5f;
            s[12] = bxn + bwn * 0.5f;
            s[13] = byn + bhn * 0.5f;
            s[14] = tarea;
            s[15] = 0.0f;
        }

        int cnt = 0;
        for (int bb = 0; bb < NB; ++bb) {
            const unsigned long long m = __ballot(timg == bb);
            if (t == 0) sball[bb] = m;
            if (t == bb) cnt = (int)__popcll(m);
        }
        int inc = cnt;
        #pragma unroll
        for (int d = 1; d < 32; d <<= 1) {
            const int v = __shfl_up(inc, d);
            if (t >= d) inc += v;
        }
        if (t < NB) soff[t] = inc - cnt;
        if (t == NB - 1) soff[NB] = inc;
        if (isT) {
            const unsigned long long m = sball[timg];
            const int rank = (int)__popcll(m & ((1ULL << t) - 1ULL));
            sord[soff[timg] + rank] = t;
        }
    }

    // ---------- decode 2 cells (fully unrolled, all static indices) ----------
    const float p0[CPT] = {v0.x, v0.y};
    const float p1[CPT] = {v1.x, v1.y};
    const float p2[CPT] = {v2.x, v2.y};
    const float p3[CPT] = {v3.x, v3.y};
    const float p4[CPT] = {v4.x, v4.y};
    const float p5[CPT] = {v5.x, v5.y};

    const float sa_w = (a == 0) ? 1.25f  : ((a == 1) ? 2.0f  : 4.125f);
    const float sa_h = (a == 0) ? 1.625f : ((a == 1) ? 3.75f : 2.875f);

    float cxv[CPT], cyv[CPT], pcf[CPT], pcl[CPT];
    float px1[CPT], py1[CPT], px2[CPT], py2[CPT], par[CPT];
    float o12[CPT * 6];

    #pragma unroll
    for (int c = 0; c < CPT; ++c) {
        const float cx    = 1.0f / (1.0f + __expf(-p0[c]));
        const float cy    = 1.0f / (1.0f + __expf(-p1[c]));
        const float pconf = 1.0f / (1.0f + __expf(-p4[c]));
        const float pcls  = 1.0f / (1.0f + __expf(-p5[c]));
        const float bx = cx + (float)(gw0 + c);
        const float by = cy + (float)gh;
        const float bw = __expf(p2[c]) * sa_w;
        const float bh = __expf(p3[c]) * sa_h;

        o12[c * 6 + 0] = bx * 8.0f;
        o12[c * 6 + 1] = by * 8.0f;
        o12[c * 6 + 2] = bw * 8.0f;
        o12[c * 6 + 3] = bh * 8.0f;
        o12[c * 6 + 4] = pconf;
        o12[c * 6 + 5] = pcls;

        const float pxc = bx * (1.0f / NGW), pyc = by * (1.0f / NGH);
        const float pwn = bw * (1.0f / NGW), phn = bh * (1.0f / NGH);
        cxv[c] = cx; cyv[c] = cy; pcf[c] = pconf; pcl[c] = pcls;
        px1[c] = pxc - pwn * 0.5f; py1[c] = pyc - phn * 0.5f;
        px2[c] = pxc + pwn * 0.5f; py2[c] = pyc + phn * 0.5f;
        par[c] = pwn * phn;
    }

    // ---------- stage output tile in LDS (48B/lane stride: 2 lanes/bank = free) ----------
    stage[tx * 3 + 0] = make_float4(o12[0], o12[1], o12[2],  o12[3]);
    stage[tx * 3 + 1] = make_float4(o12[4], o12[5], o12[6],  o12[7]);
    stage[tx * 3 + 2] = make_float4(o12[8], o12[9], o12[10], o12[11]);

    __syncthreads();   // publishes stage[] AND st/soff/sord

    // ---------- dense output stores: 1KB contiguous per wave-instruction ----------
    {
        float4* obase = (float4*)(out + (size_t)bid * (BLK * CPT * 6));
        obase[0 * BLK + tx] = stage[0 * BLK + tx];
        obase[1 * BLK + tx] = stage[1 * BLK + tx];
        obase[2 * BLK + tx] = stage[2 * BLK + tx];
    }

    // ---------- per-cell losses over this image's targets only (overlaps store drain) ----------
    float best[CPT] = {-1.f, -1.f};
    int   so[CPT]   = {-1, -1};
    {
        const int j1 = soff[b + 1];
        for (int j = soff[b]; j < j1; ++j) {
            const int t = sord[j];
            const float* s = st + t * 16;          // LDS broadcast reads
            const float s1 = s[1], s2f = s[2], s3f = s[3], s4f = s[4];
            const float x1 = s[10], y1 = s[11], x2 = s[12], y2 = s[13], ta = s[14];
            const bool vmatch = (s1 != 0.0f) && ((int)s2f == a) && ((int)s3f == gh);
            #pragma unroll
            for (int c = 0; c < CPT; ++c) {
                const float iw = fmaxf(fminf(x2, px2[c]) - fmaxf(x1, px1[c]), 0.0f);
                const float ih = fmaxf(fminf(y2, py2[c]) - fmaxf(y1, py1[c]), 0.0f);
                const float inter = iw * ih;
                const float iou = inter / (((ta + par[c]) - inter) + 1e-16f);
                if (iou > best[c]) best[c] = iou;
                if (vmatch && ((int)s4f == gw0 + c)) so[c] = t;   // last match wins
            }
        }
    }

    float lxy = 0.f, lwh = 0.f, lconf = 0.f, lcls = 0.f;
    #pragma unroll
    for (int c = 0; c < CPT; ++c) {
        if (so[c] >= 0) {
            const float* s = st + so[c] * 16;
            const float sc = s[9], s2 = sc * sc;
            const float dx = cxv[c] - s[5], dy = cyv[c] - s[6];
            const float dw = p2[c] - s[7], dh = p3[c] - s[8];
            lxy   += (dx * dx + dy * dy) * s2;
            lwh   += (dw * dw + dh * dh) * s2;
            lconf += -fmaxf(__logf(pcf[c]), -100.0f);
            lcls  += -fmaxf(__logf(pcl[c]), -100.0f);
        } else if (best[c] <= 0.5f) {
            lconf += -fmaxf(__logf(1.0f - pcf[c]), -100.0f);
        }
    }

    // ---------- block reduction -> per-block partial ----------
    #pragma unroll
    for (int off = 32; off > 0; off >>= 1) {
        lxy   += __shfl_down(lxy, off);
        lwh   += __shfl_down(lwh, off);
        lconf += __shfl_down(lconf, off);
        lcls  += __shfl_down(lcls, off);
    }
    const int lane = tx & 63, wv = tx >> 6;
    if (lane == 0) { red[wv][0] = lxy; red[wv][1] = lwh; red[wv][2] = lconf; red[wv][3] = lcls; }
    __syncthreads();
    if (tx == 0) {
        // agent-scope stores bypass the (non-coherent) XCD L2
        __hip_atomic_store(&partials[bid * 4 + 0], red[0][0] + red[1][0] + red[2][0] + red[3][0], __ATOMIC_RELAXED, __HIP_MEMORY_SCOPE_AGENT);
        __hip_atomic_store(&partials[bid * 4 + 1], red[0][1] + red[1][1] + red[2][1] + red[3][1], __ATOMIC_RELAXED, __HIP_MEMORY_SCOPE_AGENT);
        __hip_atomic_store(&partials[bid * 4 + 2], red[0][2] + red[1][2] + red[2][2] + red[3][2], __ATOMIC_RELAXED, __HIP_MEMORY_SCOPE_AGENT);
        __hip_atomic_store(&partials[bid * 4 + 3], red[0][3] + red[1][3] + red[2][3] + red[3][3], __ATOMIC_RELAXED, __HIP_MEMORY_SCOPE_AGENT);
        asm volatile("s_waitcnt vmcnt(0)" ::: "memory");   // partials at coherence point
        __hip_atomic_store(&flags[bid], MAGIC, __ATOMIC_RELAXED, __HIP_MEMORY_SCOPE_AGENT);
    }

    // ---------- block 0: arrive-then-exit final reduce ----------
    if (bid == 0) {
        // latency-parallel poll: 5 independent guarded loads per thread per pass
        for (;;) {
            const unsigned f0 = __hip_atomic_load(&flags[tx], __ATOMIC_RELAXED, __HIP_MEMORY_SCOPE_AGENT);
            const unsigned f1 = __hip_atomic_load(&flags[tx + BLK], __ATOMIC_RELAXED, __HIP_MEMORY_SCOPE_AGENT);
            const unsigned f2 = __hip_atomic_load(&flags[tx + 2 * BLK], __ATOMIC_RELAXED, __HIP_MEMORY_SCOPE_AGENT);
            const unsigned f3 = __hip_atomic_load(&flags[tx + 3 * BLK], __ATOMIC_RELAXED, __HIP_MEMORY_SCOPE_AGENT);
            const unsigned f4_ = (tx + 4 * BLK < NBLKS)
                ? __hip_atomic_load(&flags[tx + 4 * BLK], __ATOMIC_RELAXED, __HIP_MEMORY_SCOPE_AGENT)
                : MAGIC;
            const int ok = (f0 == MAGIC) & (f1 == MAGIC) & (f2 == MAGIC) & (f3 == MAGIC) & (f4_ == MAGIC);
            if (__syncthreads_and(ok)) break;
            __builtin_amdgcn_s_sleep(16);
        }

        // latency-parallel reduce: 20 independent guarded loads per thread
        float a0 = 0.f, a1 = 0.f, a2 = 0.f, a3 = 0.f;
        #pragma unroll
        for (int k = 0; k < 5; ++k) {
            const int i = tx + k * BLK;
            if (i < NBLKS) {
                const float q0 = __hip_atomic_load(&partials[i * 4 + 0], __ATOMIC_RELAXED, __HIP_MEMORY_SCOPE_AGENT);
                const float q1 = __hip_atomic_load(&partials[i * 4 + 1], __ATOMIC_RELAXED, __HIP_MEMORY_SCOPE_AGENT);
                const float q2 = __hip_atomic_load(&partials[i * 4 + 2], __ATOMIC_RELAXED, __HIP_MEMORY_SCOPE_AGENT);
                const float q3 = __hip_atomic_load(&partials[i * 4 + 3], __ATOMIC_RELAXED, __HIP_MEMORY_SCOPE_AGENT);
                a0 += q0; a1 += q1; a2 += q2; a3 += q3;
            }
        }
        #pragma unroll
        for (int off = 32; off > 0; off >>= 1) {
            a0 += __shfl_down(a0, off);
            a1 += __shfl_down(a1, off);
            a2 += __shfl_down(a2, off);
            a3 += __shfl_down(a3, off);
        }
        if (lane == 0) { red[wv][0] = a0; red[wv][1] = a1; red[wv][2] = a2; red[wv][3] = a3; }
        __syncthreads();
        if (tx == 0) {
            const float s0 = red[0][0] + red[1][0] + red[2][0] + red[3][0];
            const float s1 = red[0][1] + red[1][1] + red[2][1] + red[3][1];
            const float s2 = red[0][2] + red[1][2] + red[2][2] + red[3][2];
            const float s3 = red[0][3] + red[1][3] + red[2][3] + red[3][3];
            lossbuf[1] = s0;
            lossbuf[2] = s1;
            lossbuf[3] = s2;
            lossbuf[4] = s3;
            lossbuf[0] = ((s0 + s1) + s2) + s3;
        }
    }
}

extern "C" void kernel_launch(void* const* d_in, const int* in_sizes, int n_in,
                              void* d_out, int out_size, void* d_ws, size_t ws_size,
                              hipStream_t stream) {
    const float* x   = (const float*)d_in[0];
    const float* tgt = (const float*)d_in[1];
    float* out          = (float*)d_out;
    float* lossbuf      = out + NOUT;
    float* partials     = (float*)d_ws;                          // 1083*4 floats
    unsigned int* flags = (unsigned int*)(partials + NBLKS * 4); // 1083 u32

    // Launch 1: the full round-13 kernel (current best, 16.09 us end-to-end).
    hipLaunchKernelGGL(yolo_main, dim3(NBLKS), dim3(BLK), 0, stream,
                       x, tgt, out, partials, flags, lossbuf);
    // Launch 2 (DIAGNOSTIC ablation): decode+store only, rewrites identical
    // out values. dur_us - 16.1 isolates the streaming phase's true cost.
    hipLaunchKernelGGL(yolo_decode_only, dim3(NBLKS), dim3(BLK), 0, stream,
                       x, out);
    (void)in_sizes; (void)n_in; (void)out_size; (void)ws_size;
}

// Round 15
// 17.338 us; speedup vs baseline: 1.2972x; 1.2972x over previous
//
#include <hip/hip_runtime.h>

#define NB 32
#define NA 3
#define NGH 76
#define NGW 76
#define NT 48
#define PLANE (NGH * NGW)          // 5776
#define NCELL (NB * NA * PLANE)    // 554496
#define NOUT  (NCELL * 6)          // 3326976
#define CPT 2                      // cells per thread (consecutive pair)
#define BLK 256                    // 4 waves; 1083 blocks
#define NTHREAD (NCELL / CPT)      // 277248
#define NBLKS (NTHREAD / BLK)      // 1083
#define MAGIC 0x59A10C47u

static_assert(NTHREAD % BLK == 0, "grid must divide evenly");
static_assert(5 * BLK >= NBLKS, "poll covers all flags in one unrolled pass");

// st layout per target (16 floats), one copy PER WAVE (no inter-wave barrier):
// 0: timg  1: valid  2: bi  3: gj  4: gi  5: tx  6: ty  7: tw  8: th  9: sc
// 10..13: x1 y1 x2 y2 (normalized xyxy)  14: area  15: pad

__launch_bounds__(BLK, 6)
__global__ void yolo_main(const float* __restrict__ x,
                          const float* __restrict__ tgt,
                          float* __restrict__ out,
                          float* __restrict__ partials,      // [NBLKS][4]
                          unsigned int* __restrict__ flags,  // [NBLKS]
                          float* __restrict__ lossbuf) {
    __shared__ float st[4][NT * 16];      // 12KB: per-wave target records
    __shared__ int   soff[4][NB + 1];     // per-wave CSR offsets
    __shared__ int   sord[4][NT];         // per-wave CSR order
    __shared__ float red[4][4];

    const int tx  = threadIdx.x;
    const int bid = blockIdx.x;
    const int lane = tx & 63, wv = tx >> 6;
    const int tid = bid * BLK + tx;
    const int g   = tid * CPT;                // first of 2 consecutive cells (even)

    const int gw0 = g % NGW;                  // even, pair never straddles a row
    const int gh  = (g / NGW) % NGH;
    const int a   = (g / PLANE) % NA;
    const int b   = g / (NA * PLANE);

    // ---------- vectorized channel loads (issue before target prep) ----------
    const float* xp = x + (size_t)(b * (NA * 6) + a * 6) * PLANE + (g % PLANE);
    const float2 v0 = *(const float2*)(xp);
    const float2 v1 = *(const float2*)(xp + PLANE);
    const float2 v2 = *(const float2*)(xp + 2 * PLANE);
    const float2 v3 = *(const float2*)(xp + 3 * PLANE);
    const float2 v4 = *(const float2*)(xp + 4 * PLANE);
    const float2 v5 = *(const float2*)(xp + 5 * PLANE);

    // ---------- EVERY wave: target prep + per-image CSR (wave-local, no barrier) ----------
    {
        const int t = lane;
        const bool isT = (t < NT);
        int timg = 999;                       // sentinel: matches no image
        if (isT) {
            const float t00 = tgt[0];
            const float* tr = tgt + t * 6;
            timg = (int)(tr[0] - t00);
            const float bxn = tr[1], byn = tr[2], bwn = tr[3], bhn = tr[4];

            const float gx = bxn * (float)NGW;
            const float gy = byn * (float)NGH;
            const int gi = (int)gx;
            const int gj = (int)gy;
            const float tarea = bwn * bhn;

            const float aw_px[9] = {10.f,16.f,33.f,30.f,62.f,59.f,116.f,156.f,373.f};
            const float ah_px[9] = {13.f,30.f,23.f,61.f,45.f,119.f,90.f,198.f,326.f};
            int bidx = 0; float biou = -1e30f;
            #pragma unroll
            for (int k = 0; k < 9; ++k) {
                const float aw = aw_px[k] / 608.0f;
                const float ah = ah_px[k] / 608.0f;
                const float wi = fminf(aw, bwn) * fminf(ah, bhn);
                const float un = ((aw * ah + 1e-16f) + tarea) - wi;
                const float iou = wi / un;
                if (iou > biou) { biou = iou; bidx = k; }
            }
            const bool inm = (bidx >= 0) && (bidx <= 2);
            const bool valid = inm && (gi < NGW) && (gj < NGH) && (gi >= 0) && (gj >= 0);
            const int bic = bidx < 0 ? 0 : (bidx > 2 ? 2 : bidx);
            const float apw = (bic == 0) ? 10.f : ((bic == 1) ? 16.f : 33.f);
            const float aph = (bic == 0) ? 13.f : ((bic == 1) ? 30.f : 23.f);

            float* s = &st[wv][t * 16];
            s[0]  = (float)timg;
            s[1]  = valid ? 1.0f : 0.0f;
            s[2]  = (float)bidx;
            s[3]  = (float)gj;
            s[4]  = (float)gi;
            s[5]  = gx - floorf(gx);
            s[6]  = gy - floorf(gy);
            s[7]  = __logf(((bwn * (float)NGW) * 8.0f) / apw + 1e-16f);
            s[8]  = __logf(((bhn * (float)NGH) * 8.0f) / aph + 1e-16f);
            s[9]  = 2.0f - bwn * bhn;
            s[10] = bxn - bwn * 0.5f;
            s[11] = byn - bhn * 0.5f;
            s[12] = bxn + bwn * 0.5f;
            s[13] = byn + bhn * 0.5f;
            s[14] = tarea;
            s[15] = 0.0f;
        }

        // per-image counts via 32 wave-ballots; keep own-image mask in registers
        unsigned long long mymask = 0ULL;
        int cnt = 0;
        for (int bb = 0; bb < NB; ++bb) {
            const unsigned long long m = __ballot(timg == bb);
            if (t == bb) cnt = (int)__popcll(m);
            if (timg == bb) mymask = m;
        }
        // exclusive prefix over 32 counts (shuffle scan)
        int inc = cnt;
        #pragma unroll
        for (int d = 1; d < 32; d <<= 1) {
            const int v = __shfl_up(inc, d);
            if (t >= d) inc += v;
        }
        if (t < NB) soff[wv][t] = inc - cnt;
        if (t == NB - 1) soff[wv][NB] = inc;
        if (isT) {
            // offset of own image via shuffles (no LDS round-trip)
            const int incT = __shfl(inc, timg);
            const int cntT = __shfl(cnt, timg);
            const int rank = (int)__popcll(mymask & ((1ULL << t) - 1ULL));
            sord[wv][(incT - cntT) + rank] = t;
        }
    }
    // intra-wave LDS write->read visibility: drain DS queue, pin ordering (rule #18)
    __builtin_amdgcn_sched_barrier(0);
    asm volatile("s_waitcnt lgkmcnt(0)" ::: "memory");
    __builtin_amdgcn_sched_barrier(0);

    // ---------- decode 2 cells (fully unrolled, all static indices) ----------
    const float p0[CPT] = {v0.x, v0.y};
    const float p1[CPT] = {v1.x, v1.y};
    const float p2[CPT] = {v2.x, v2.y};
    const float p3[CPT] = {v3.x, v3.y};
    const float p4[CPT] = {v4.x, v4.y};
    const float p5[CPT] = {v5.x, v5.y};

    const float sa_w = (a == 0) ? 1.25f  : ((a == 1) ? 2.0f  : 4.125f);
    const float sa_h = (a == 0) ? 1.625f : ((a == 1) ? 3.75f : 2.875f);

    float cxv[CPT], cyv[CPT], pcf[CPT], pcl[CPT];
    float px1[CPT], py1[CPT], px2[CPT], py2[CPT], par[CPT];
    float o12[CPT * 6];

    #pragma unroll
    for (int c = 0; c < CPT; ++c) {
        const float cx    = 1.0f / (1.0f + __expf(-p0[c]));
        const float cy    = 1.0f / (1.0f + __expf(-p1[c]));
        const float pconf = 1.0f / (1.0f + __expf(-p4[c]));
        const float pcls  = 1.0f / (1.0f + __expf(-p5[c]));
        const float bx = cx + (float)(gw0 + c);
        const float by = cy + (float)gh;
        const float bw = __expf(p2[c]) * sa_w;
        const float bh = __expf(p3[c]) * sa_h;

        o12[c * 6 + 0] = bx * 8.0f;
        o12[c * 6 + 1] = by * 8.0f;
        o12[c * 6 + 2] = bw * 8.0f;
        o12[c * 6 + 3] = bh * 8.0f;
        o12[c * 6 + 4] = pconf;
        o12[c * 6 + 5] = pcls;

        const float pxc = bx * (1.0f / NGW), pyc = by * (1.0f / NGH);
        const float pwn = bw * (1.0f / NGW), phn = bh * (1.0f / NGH);
        cxv[c] = cx; cyv[c] = cy; pcf[c] = pconf; pcl[c] = pcls;
        px1[c] = pxc - pwn * 0.5f; py1[c] = pyc - phn * 0.5f;
        px2[c] = pxc + pwn * 0.5f; py2[c] = pyc + phn * 0.5f;
        par[c] = pwn * phn;
    }

    // ---------- direct coalesced output: 48 contiguous bytes per thread ----------
    {
        float4* ob = (float4*)(out + (size_t)g * 6);
        ob[0] = make_float4(o12[0], o12[1], o12[2],  o12[3]);
        ob[1] = make_float4(o12[4], o12[5], o12[6],  o12[7]);
        ob[2] = make_float4(o12[8], o12[9], o12[10], o12[11]);
    }

    // ---------- per-cell losses over this image's targets (wave-local CSR) ----------
    float best[CPT] = {-1.f, -1.f};
    int   so[CPT]   = {-1, -1};
    {
        const int j1 = soff[wv][b + 1];
        for (int j = soff[wv][b]; j < j1; ++j) {
            const int t = sord[wv][j];
            const float* s = &st[wv][t * 16];      // LDS broadcast reads
            const float s1 = s[1], s2f = s[2], s3f = s[3], s4f = s[4];
            const float x1 = s[10], y1 = s[11], x2 = s[12], y2 = s[13], ta = s[14];
            const bool vmatch = (s1 != 0.0f) && ((int)s2f == a) && ((int)s3f == gh);
            #pragma unroll
            for (int c = 0; c < CPT; ++c) {
                const float iw = fmaxf(fminf(x2, px2[c]) - fmaxf(x1, px1[c]), 0.0f);
                const float ih = fmaxf(fminf(y2, py2[c]) - fmaxf(y1, py1[c]), 0.0f);
                const float inter = iw * ih;
                const float iou = inter / (((ta + par[c]) - inter) + 1e-16f);
                if (iou > best[c]) best[c] = iou;
                if (vmatch && ((int)s4f == gw0 + c)) so[c] = t;   // last match wins
            }
        }
    }

    float lxy = 0.f, lwh = 0.f, lconf = 0.f, lcls = 0.f;
    #pragma unroll
    for (int c = 0; c < CPT; ++c) {
        if (so[c] >= 0) {
            const float* s = &st[wv][so[c] * 16];
            const float sc = s[9], s2 = sc * sc;
            const float dx = cxv[c] - s[5], dy = cyv[c] - s[6];
            const float dw = p2[c] - s[7], dh = p3[c] - s[8];
            lxy   += (dx * dx + dy * dy) * s2;
            lwh   += (dw * dw + dh * dh) * s2;
            lconf += -fmaxf(__logf(pcf[c]), -100.0f);
            lcls  += -fmaxf(__logf(pcl[c]), -100.0f);
        } else if (best[c] <= 0.5f) {
            lconf += -fmaxf(__logf(1.0f - pcf[c]), -100.0f);
        }
    }

    // ---------- block reduction -> per-block partial (single barrier) ----------
    #pragma unroll
    for (int off = 32; off > 0; off >>= 1) {
        lxy   += __shfl_down(lxy, off);
        lwh   += __shfl_down(lwh, off);
        lconf += __shfl_down(lconf, off);
        lcls  += __shfl_down(lcls, off);
    }
    if (lane == 0) { red[wv][0] = lxy; red[wv][1] = lwh; red[wv][2] = lconf; red[wv][3] = lcls; }
    __syncthreads();
    if (tx == 0) {
        // agent-scope stores bypass the (non-coherent) XCD L2
        __hip_atomic_store(&partials[bid * 4 + 0], red[0][0] + red[1][0] + red[2][0] + red[3][0], __ATOMIC_RELAXED, __HIP_MEMORY_SCOPE_AGENT);
        __hip_atomic_store(&partials[bid * 4 + 1], red[0][1] + red[1][1] + red[2][1] + red[3][1], __ATOMIC_RELAXED, __HIP_MEMORY_SCOPE_AGENT);
        __hip_atomic_store(&partials[bid * 4 + 2], red[0][2] + red[1][2] + red[2][2] + red[3][2], __ATOMIC_RELAXED, __HIP_MEMORY_SCOPE_AGENT);
        __hip_atomic_store(&partials[bid * 4 + 3], red[0][3] + red[1][3] + red[2][3] + red[3][3], __ATOMIC_RELAXED, __HIP_MEMORY_SCOPE_AGENT);
        asm volatile("s_waitcnt vmcnt(0)" ::: "memory");   // partials at coherence point
        __hip_atomic_store(&flags[bid], MAGIC, __ATOMIC_RELAXED, __HIP_MEMORY_SCOPE_AGENT);
    }

    // ---------- block 0: arrive-then-exit final reduce ----------
    if (bid == 0) {
        // latency-parallel poll: 5 independent guarded loads per thread per pass
        for (;;) {
            const unsigned f0 = __hip_atomic_load(&flags[tx], __ATOMIC_RELAXED, __HIP_MEMORY_SCOPE_AGENT);
            const unsigned f1 = __hip_atomic_load(&flags[tx + BLK], __ATOMIC_RELAXED, __HIP_MEMORY_SCOPE_AGENT);
            const unsigned f2 = __hip_atomic_load(&flags[tx + 2 * BLK], __ATOMIC_RELAXED, __HIP_MEMORY_SCOPE_AGENT);
            const unsigned f3 = __hip_atomic_load(&flags[tx + 3 * BLK], __ATOMIC_RELAXED, __HIP_MEMORY_SCOPE_AGENT);
            const unsigned f4_ = (tx + 4 * BLK < NBLKS)
                ? __hip_atomic_load(&flags[tx + 4 * BLK], __ATOMIC_RELAXED, __HIP_MEMORY_SCOPE_AGENT)
                : MAGIC;
            const int ok = (f0 == MAGIC) & (f1 == MAGIC) & (f2 == MAGIC) & (f3 == MAGIC) & (f4_ == MAGIC);
            if (__syncthreads_and(ok)) break;
            __builtin_amdgcn_s_sleep(2);   // fine-grained poll quantum (128 cyc)
        }

        // latency-parallel reduce: 20 independent guarded loads per thread
        float a0 = 0.f, a1 = 0.f, a2 = 0.f, a3 = 0.f;
        #pragma unroll
        for (int k = 0; k < 5; ++k) {
            const int i = tx + k * BLK;
            if (i < NBLKS) {
                const float q0 = __hip_atomic_load(&partials[i * 4 + 0], __ATOMIC_RELAXED, __HIP_MEMORY_SCOPE_AGENT);
                const float q1 = __hip_atomic_load(&partials[i * 4 + 1], __ATOMIC_RELAXED, __HIP_MEMORY_SCOPE_AGENT);
                const float q2 = __hip_atomic_load(&partials[i * 4 + 2], __ATOMIC_RELAXED, __HIP_MEMORY_SCOPE_AGENT);
                const float q3 = __hip_atomic_load(&partials[i * 4 + 3], __ATOMIC_RELAXED, __HIP_MEMORY_SCOPE_AGENT);
                a0 += q0; a1 += q1; a2 += q2; a3 += q3;
            }
        }
        #pragma unroll
        for (int off = 32; off > 0; off >>= 1) {
            a0 += __shfl_down(a0, off);
            a1 += __shfl_down(a1, off);
            a2 += __shfl_down(a2, off);
            a3 += __shfl_down(a3, off);
        }
        __syncthreads();   // red[] reuse
        if (lane == 0) { red[wv][0] = a0; red[wv][1] = a1; red[wv][2] = a2; red[wv][3] = a3; }
        __syncthreads();
        if (tx == 0) {
            const float s0 = red[0][0] + red[1][0] + red[2][0] + red[3][0];
            const float s1 = red[0][1] + red[1][1] + red[2][1] + red[3][1];
            const float s2 = red[0][2] + red[1][2] + red[2][2] + red[3][2];
            const float s3 = red[0][3] + red[1][3] + red[2][3] + red[3][3];
            lossbuf[1] = s0;
            lossbuf[2] = s1;
            lossbuf[3] = s2;
            lossbuf[4] = s3;
            lossbuf[0] = ((s0 + s1) + s2) + s3;
        }
    }
}

extern "C" void kernel_launch(void* const* d_in, const int* in_sizes, int n_in,
                              void* d_out, int out_size, void* d_ws, size_t ws_size,
                              hipStream_t stream) {
    const float* x   = (const float*)d_in[0];
    const float* tgt = (const float*)d_in[1];
    float* out          = (float*)d_out;
    float* lossbuf      = out + NOUT;
    float* partials     = (float*)d_ws;                          // 1083*4 floats
    unsigned int* flags = (unsigned int*)(partials + NBLKS * 4); // 1083 u32

    hipLaunchKernelGGL(yolo_main, dim3(NBLKS), dim3(BLK), 0, stream,
                       x, tgt, out, partials, flags, lossbuf);
    (void)in_sizes; (void)n_in; (void)out_size; (void)ws_size;
}

// Round 17
// 14.697 us; speedup vs baseline: 1.5303x; 1.1797x over previous
//
#include <hip/hip_runtime.h>

#define NB 32
#define NA 3
#define NGH 76
#define NGW 76
#define NT 48
#define PLANE (NGH * NGW)          // 5776
#define NCELL (NB * NA * PLANE)    // 554496
#define NOUT  (NCELL * 6)          // 3326976
#define CPT 2                      // cells per thread (consecutive pair)
#define BLK 256                    // 4 waves; 1083 blocks
#define NTHREAD (NCELL / CPT)      // 277248
#define NBLKS (NTHREAD / BLK)      // 1083
#define MAGIC 0x59A10C47u

static_assert(NTHREAD % BLK == 0, "grid must divide evenly");
static_assert(5 * BLK >= NBLKS, "poll covers all flags in one unrolled pass");

// native clang vector type: accepted by __builtin_nontemporal_store
typedef float f4 __attribute__((ext_vector_type(4)));

// st layout per target (16 floats):
// 0: timg  1: valid  2: bi  3: gj  4: gi  5: tx  6: ty  7: tw  8: th  9: sc
// 10..13: x1 y1 x2 y2 (normalized xyxy)  14: area  15: pad

__launch_bounds__(BLK, 6)
__global__ void yolo_main(const float* __restrict__ x,
                          const float* __restrict__ tgt,
                          float* __restrict__ out,
                          float* __restrict__ partials,      // [NBLKS][4]
                          unsigned int* __restrict__ flags,  // [NBLKS]
                          float* __restrict__ lossbuf) {
    __shared__ float st[NT * 16];
    __shared__ unsigned long long sball[NB];
    __shared__ int soff[NB + 1];
    __shared__ int sord[NT];
    __shared__ float red[4][4];
    __shared__ f4 stage[BLK * 3];             // 12KB output tile staging

    const int tx  = threadIdx.x;
    const int bid = blockIdx.x;
    const int tid = bid * BLK + tx;
    const int g   = tid * CPT;                // first of 2 consecutive cells (even)

    const int gw0 = g % NGW;                  // even, pair never straddles a row
    const int gh  = (g / NGW) % NGH;
    const int a   = (g / PLANE) % NA;
    const int b   = g / (NA * PLANE);

    // ---------- vectorized channel loads (issue before target prep) ----------
    const float* xp = x + (size_t)(b * (NA * 6) + a * 6) * PLANE + (g % PLANE);
    const float2 v0 = *(const float2*)(xp);
    const float2 v1 = *(const float2*)(xp + PLANE);
    const float2 v2 = *(const float2*)(xp + 2 * PLANE);
    const float2 v3 = *(const float2*)(xp + 3 * PLANE);
    const float2 v4 = *(const float2*)(xp + 4 * PLANE);
    const float2 v5 = *(const float2*)(xp + 5 * PLANE);

    // ---------- wave 0: target prep + per-image CSR (ballot-based) ----------
    if (tx < 64) {
        const int t = tx;
        const bool isT = (t < NT);
        int timg = 999;                       // sentinel: matches no image
        if (isT) {
            const float t00 = tgt[0];
            const float* tr = tgt + t * 6;
            timg = (int)(tr[0] - t00);
            const float bxn = tr[1], byn = tr[2], bwn = tr[3], bhn = tr[4];

            const float gx = bxn * (float)NGW;
            const float gy = byn * (float)NGH;
            const int gi = (int)gx;
            const int gj = (int)gy;
            const float tarea = bwn * bhn;

            const float aw_px[9] = {10.f,16.f,33.f,30.f,62.f,59.f,116.f,156.f,373.f};
            const float ah_px[9] = {13.f,30.f,23.f,61.f,45.f,119.f,90.f,198.f,326.f};
            int bidx = 0; float biou = -1e30f;
            #pragma unroll
            for (int k = 0; k < 9; ++k) {
                const float aw = aw_px[k] / 608.0f;
                const float ah = ah_px[k] / 608.0f;
                const float wi = fminf(aw, bwn) * fminf(ah, bhn);
                const float un = ((aw * ah + 1e-16f) + tarea) - wi;
                const float iou = wi / un;
                if (iou > biou) { biou = iou; bidx = k; }
            }
            const bool inm = (bidx >= 0) && (bidx <= 2);
            const bool valid = inm && (gi < NGW) && (gj < NGH) && (gi >= 0) && (gj >= 0);
            const int bic = bidx < 0 ? 0 : (bidx > 2 ? 2 : bidx);
            const float apw = (bic == 0) ? 10.f : ((bic == 1) ? 16.f : 33.f);
            const float aph = (bic == 0) ? 13.f : ((bic == 1) ? 30.f : 23.f);

            float* s = st + t * 16;
            s[0]  = (float)timg;
            s[1]  = valid ? 1.0f : 0.0f;
            s[2]  = (float)bidx;
            s[3]  = (float)gj;
            s[4]  = (float)gi;
            s[5]  = gx - floorf(gx);
            s[6]  = gy - floorf(gy);
            s[7]  = __logf(((bwn * (float)NGW) * 8.0f) / apw + 1e-16f);
            s[8]  = __logf(((bhn * (float)NGH) * 8.0f) / aph + 1e-16f);
            s[9]  = 2.0f - bwn * bhn;
            s[10] = bxn - bwn * 0.5f;
            s[11] = byn - bhn * 0.5f;
            s[12] = bxn + bwn * 0.5f;
            s[13] = byn + bhn * 0.5f;
            s[14] = tarea;
            s[15] = 0.0f;
        }

        int cnt = 0;
        for (int bb = 0; bb < NB; ++bb) {
            const unsigned long long m = __ballot(timg == bb);
            if (t == 0) sball[bb] = m;
            if (t == bb) cnt = (int)__popcll(m);
        }
        int inc = cnt;
        #pragma unroll
        for (int d = 1; d < 32; d <<= 1) {
            const int v = __shfl_up(inc, d);
            if (t >= d) inc += v;
        }
        if (t < NB) soff[t] = inc - cnt;
        if (t == NB - 1) soff[NB] = inc;
        if (isT) {
            const unsigned long long m = sball[timg];
            const int rank = (int)__popcll(m & ((1ULL << t) - 1ULL));
            sord[soff[timg] + rank] = t;
        }
    }

    // ---------- decode 2 cells (fully unrolled, all static indices) ----------
    const float p0[CPT] = {v0.x, v0.y};
    const float p1[CPT] = {v1.x, v1.y};
    const float p2[CPT] = {v2.x, v2.y};
    const float p3[CPT] = {v3.x, v3.y};
    const float p4[CPT] = {v4.x, v4.y};
    const float p5[CPT] = {v5.x, v5.y};

    const float sa_w = (a == 0) ? 1.25f  : ((a == 1) ? 2.0f  : 4.125f);
    const float sa_h = (a == 0) ? 1.625f : ((a == 1) ? 3.75f : 2.875f);

    float cxv[CPT], cyv[CPT], pcf[CPT], pcl[CPT];
    float px1[CPT], py1[CPT], px2[CPT], py2[CPT], par[CPT];
    float o12[CPT * 6];

    #pragma unroll
    for (int c = 0; c < CPT; ++c) {
        const float cx    = 1.0f / (1.0f + __expf(-p0[c]));
        const float cy    = 1.0f / (1.0f + __expf(-p1[c]));
        const float pconf = 1.0f / (1.0f + __expf(-p4[c]));
        const float pcls  = 1.0f / (1.0f + __expf(-p5[c]));
        const float bx = cx + (float)(gw0 + c);
        const float by = cy + (float)gh;
        const float bw = __expf(p2[c]) * sa_w;
        const float bh = __expf(p3[c]) * sa_h;

        o12[c * 6 + 0] = bx * 8.0f;
        o12[c * 6 + 1] = by * 8.0f;
        o12[c * 6 + 2] = bw * 8.0f;
        o12[c * 6 + 3] = bh * 8.0f;
        o12[c * 6 + 4] = pconf;
        o12[c * 6 + 5] = pcls;

        const float pxc = bx * (1.0f / NGW), pyc = by * (1.0f / NGH);
        const float pwn = bw * (1.0f / NGW), phn = bh * (1.0f / NGH);
        cxv[c] = cx; cyv[c] = cy; pcf[c] = pconf; pcl[c] = pcls;
        px1[c] = pxc - pwn * 0.5f; py1[c] = pyc - phn * 0.5f;
        px2[c] = pxc + pwn * 0.5f; py2[c] = pyc + phn * 0.5f;
        par[c] = pwn * phn;
    }

    // ---------- stage output tile in LDS (48B/lane stride: 2 lanes/bank = free) ----------
    {
        f4 s0; s0.x = o12[0]; s0.y = o12[1]; s0.z = o12[2];  s0.w = o12[3];
        f4 s1; s1.x = o12[4]; s1.y = o12[5]; s1.z = o12[6];  s1.w = o12[7];
        f4 s2; s2.x = o12[8]; s2.y = o12[9]; s2.z = o12[10]; s2.w = o12[11];
        stage[tx * 3 + 0] = s0;
        stage[tx * 3 + 1] = s1;
        stage[tx * 3 + 2] = s2;
    }

    __syncthreads();   // publishes stage[] AND st/soff/sord

    // ---------- dense NONTEMPORAL stores: full-line writes, no L2 write-allocate ----------
    {
        f4* obase = (f4*)(out + (size_t)bid * (BLK * CPT * 6));
        __builtin_nontemporal_store(stage[0 * BLK + tx], obase + 0 * BLK + tx);
        __builtin_nontemporal_store(stage[1 * BLK + tx], obase + 1 * BLK + tx);
        __builtin_nontemporal_store(stage[2 * BLK + tx], obase + 2 * BLK + tx);
    }

    // ---------- per-cell losses over this image's targets only (overlaps store drain) ----------
    float best[CPT] = {-1.f, -1.f};
    int   so[CPT]   = {-1, -1};
    {
        const int j1 = soff[b + 1];
        for (int j = soff[b]; j < j1; ++j) {
            const int t = sord[j];
            const float* s = st + t * 16;          // LDS broadcast reads
            const float s1 = s[1], s2f = s[2], s3f = s[3], s4f = s[4];
            const float x1 = s[10], y1 = s[11], x2 = s[12], y2 = s[13], ta = s[14];
            const bool vmatch = (s1 != 0.0f) && ((int)s2f == a) && ((int)s3f == gh);
            #pragma unroll
            for (int c = 0; c < CPT; ++c) {
                const float iw = fmaxf(fminf(x2, px2[c]) - fmaxf(x1, px1[c]), 0.0f);
                const float ih = fmaxf(fminf(y2, py2[c]) - fmaxf(y1, py1[c]), 0.0f);
                const float inter = iw * ih;
                const float iou = inter / (((ta + par[c]) - inter) + 1e-16f);
                if (iou > best[c]) best[c] = iou;
                if (vmatch && ((int)s4f == gw0 + c)) so[c] = t;   // last match wins
            }
        }
    }

    float lxy = 0.f, lwh = 0.f, lconf = 0.f, lcls = 0.f;
    #pragma unroll
    for (int c = 0; c < CPT; ++c) {
        if (so[c] >= 0) {
            const float* s = st + so[c] * 16;
            const float sc = s[9], s2 = sc * sc;
            const float dx = cxv[c] - s[5], dy = cyv[c] - s[6];
            const float dw = p2[c] - s[7], dh = p3[c] - s[8];
            lxy   += (dx * dx + dy * dy) * s2;
            lwh   += (dw * dw + dh * dh) * s2;
            lconf += -fmaxf(__logf(pcf[c]), -100.0f);
            lcls  += -fmaxf(__logf(pcl[c]), -100.0f);
        } else if (best[c] <= 0.5f) {
            lconf += -fmaxf(__logf(1.0f - pcf[c]), -100.0f);
        }
    }

    // ---------- block reduction -> per-block partial ----------
    #pragma unroll
    for (int off = 32; off > 0; off >>= 1) {
        lxy   += __shfl_down(lxy, off);
        lwh   += __shfl_down(lwh, off);
        lconf += __shfl_down(lconf, off);
        lcls  += __shfl_down(lcls, off);
    }
    const int lane = tx & 63, wv = tx >> 6;
    if (lane == 0) { red[wv][0] = lxy; red[wv][1] = lwh; red[wv][2] = lconf; red[wv][3] = lcls; }
    __syncthreads();
    if (tx == 0) {
        // agent-scope stores bypass the (non-coherent) XCD L2
        __hip_atomic_store(&partials[bid * 4 + 0], red[0][0] + red[1][0] + red[2][0] + red[3][0], __ATOMIC_RELAXED, __HIP_MEMORY_SCOPE_AGENT);
        __hip_atomic_store(&partials[bid * 4 + 1], red[0][1] + red[1][1] + red[2][1] + red[3][1], __ATOMIC_RELAXED, __HIP_MEMORY_SCOPE_AGENT);
        __hip_atomic_store(&partials[bid * 4 + 2], red[0][2] + red[1][2] + red[2][2] + red[3][2], __ATOMIC_RELAXED, __HIP_MEMORY_SCOPE_AGENT);
        __hip_atomic_store(&partials[bid * 4 + 3], red[0][3] + red[1][3] + red[2][3] + red[3][3], __ATOMIC_RELAXED, __HIP_MEMORY_SCOPE_AGENT);
        asm volatile("s_waitcnt vmcnt(0)" ::: "memory");   // partials (and out stores) at coherence point
        __hip_atomic_store(&flags[bid], MAGIC, __ATOMIC_RELAXED, __HIP_MEMORY_SCOPE_AGENT);
    }

    // ---------- block 0: arrive-then-exit final reduce ----------
    if (bid == 0) {
        // latency-parallel poll: 5 independent guarded loads per thread per pass
        for (;;) {
            const unsigned f0 = __hip_atomic_load(&flags[tx], __ATOMIC_RELAXED, __HIP_MEMORY_SCOPE_AGENT);
            const unsigned f1 = __hip_atomic_load(&flags[tx + BLK], __ATOMIC_RELAXED, __HIP_MEMORY_SCOPE_AGENT);
            const unsigned f2 = __hip_atomic_load(&flags[tx + 2 * BLK], __ATOMIC_RELAXED, __HIP_MEMORY_SCOPE_AGENT);
            const unsigned f3 = __hip_atomic_load(&flags[tx + 3 * BLK], __ATOMIC_RELAXED, __HIP_MEMORY_SCOPE_AGENT);
            const unsigned f4_ = (tx + 4 * BLK < NBLKS)
                ? __hip_atomic_load(&flags[tx + 4 * BLK], __ATOMIC_RELAXED, __HIP_MEMORY_SCOPE_AGENT)
                : MAGIC;
            const int ok = (f0 == MAGIC) & (f1 == MAGIC) & (f2 == MAGIC) & (f3 == MAGIC) & (f4_ == MAGIC);
            if (__syncthreads_and(ok)) break;
            __builtin_amdgcn_s_sleep(2);   // fine-grained poll quantum (128 cyc)
        }

        // latency-parallel reduce: 20 independent guarded loads per thread
        float a0 = 0.f, a1 = 0.f, a2 = 0.f, a3 = 0.f;
        #pragma unroll
        for (int k = 0; k < 5; ++k) {
            const int i = tx + k * BLK;
            if (i < NBLKS) {
                const float q0 = __hip_atomic_load(&partials[i * 4 + 0], __ATOMIC_RELAXED, __HIP_MEMORY_SCOPE_AGENT);
                const float q1 = __hip_atomic_load(&partials[i * 4 + 1], __ATOMIC_RELAXED, __HIP_MEMORY_SCOPE_AGENT);
                const float q2 = __hip_atomic_load(&partials[i * 4 + 2], __ATOMIC_RELAXED, __HIP_MEMORY_SCOPE_AGENT);
                const float q3 = __hip_atomic_load(&partials[i * 4 + 3], __ATOMIC_RELAXED, __HIP_MEMORY_SCOPE_AGENT);
                a0 += q0; a1 += q1; a2 += q2; a3 += q3;
            }
        }
        #pragma unroll
        for (int off = 32; off > 0; off >>= 1) {
            a0 += __shfl_down(a0, off);
            a1 += __shfl_down(a1, off);
            a2 += __shfl_down(a2, off);
            a3 += __shfl_down(a3, off);
        }
        __syncthreads();   // red[] reuse
        if (lane == 0) { red[wv][0] = a0; red[wv][1] = a1; red[wv][2] = a2; red[wv][3] = a3; }
        __syncthreads();
        if (tx == 0) {
            const float s0 = red[0][0] + red[1][0] + red[2][0] + red[3][0];
            const float s1 = red[0][1] + red[1][1] + red[2][1] + red[3][1];
            const float s2 = red[0][2] + red[1][2] + red[2][2] + red[3][2];
            const float s3 = red[0][3] + red[1][3] + red[2][3] + red[3][3];
            lossbuf[1] = s0;
            lossbuf[2] = s1;
            lossbuf[3] = s2;
            lossbuf[4] = s3;
            lossbuf[0] = ((s0 + s1) + s2) + s3;
        }
    }
}

extern "C" void kernel_launch(void* const* d_in, const int* in_sizes, int n_in,
                              void* d_out, int out_size, void* d_ws, size_t ws_size,
                              hipStream_t stream) {
    const float* x   = (const float*)d_in[0];
    const float* tgt = (const float*)d_in[1];
    float* out          = (float*)d_out;
    float* lossbuf      = out + NOUT;
    float* partials     = (float*)d_ws;                          // 1083*4 floats
    unsigned int* flags = (unsigned int*)(partials + NBLKS * 4); // 1083 u32

    hipLaunchKernelGGL(yolo_main, dim3(NBLKS), dim3(BLK), 0, stream,
                       x, tgt, out, partials, flags, lossbuf);
    (void)in_sizes; (void)n_in; (void)out_size; (void)ws_size;
}